// Round 1
// baseline (119.653 us; speedup 1.0000x reference)
//
#include <hip/hip_runtime.h>
#include <math.h>
#include <float.h>

#define BIGINT_F 1e10f
#define L_TOK 128
#define C_ATOM 14
#define E_DIM 256
#define K_NB 9

// strict f32: ((x*x + y*y) + z*z), no FMA contraction (match np order)
__device__ __forceinline__ float sq3(float x, float y, float z) {
    return __fadd_rn(__fadd_rn(__fmul_rn(x, x), __fmul_rn(y, y)), __fmul_rn(z, z));
}

// ---------------- h = [res_embed[S]+pos_e , mean(atom_embed[A]+atom_pos_embed[AP])] ----
__global__ void embed_kernel(const int* __restrict__ S, const int* __restrict__ RP,
                             const int* __restrict__ A, const int* __restrict__ AP,
                             const float* __restrict__ res_embed,
                             const float* __restrict__ atom_embed,
                             const float* __restrict__ atom_pos_embed,
                             float* __restrict__ h) {
    int n = blockIdx.x;
    int e = threadIdx.x;  // 0..255
    int s = S[n];
    float rp = (float)RP[n];

    // positional embedding: pairs (sin, cos) interleaved; k = e/2
    int k = e >> 1;
    float invk = powf(10000.0f, -2.0f * (float)k / (float)E_DIM);
    float ang = rp * invk;
    float pe = (e & 1) ? cosf(ang) : sinf(ang);
    h[(size_t)n * (2 * E_DIM) + e] = res_embed[s * E_DIM + e] + pe;

    __shared__ int sA[C_ATOM], sAP[C_ATOM];
    if (e < C_ATOM) { sA[e] = A[n * C_ATOM + e]; sAP[e] = AP[n * C_ATOM + e]; }
    __syncthreads();

    float sum = 0.0f, cnt = 0.0f;
    for (int c = 0; c < C_ATOM; ++c) {
        if (sAP[c] != 0) {
            sum += atom_embed[sA[c] * E_DIM + e] + atom_pos_embed[sAP[c] * E_DIM + e];
            cnt += 1.0f;
        }
    }
    h[(size_t)n * (2 * E_DIM) + E_DIM + e] = sum / (cnt + 1e-10f);
}

// ---------------- fused min-pair-dist + dual masked top-k (stable, jax-compatible) ----
__global__ void __launch_bounds__(L_TOK)
knn_kernel(const float* __restrict__ X, const int* __restrict__ AP,
           const int* __restrict__ S, const int* __restrict__ seg,
           float* __restrict__ ctx_src, float* __restrict__ ctx_dst, float* __restrict__ ctx_val,
           float* __restrict__ int_src, float* __restrict__ int_dst, float* __restrict__ int_val) {
    int bi = blockIdx.x;        // b*L + i
    int b = bi >> 7;
    int i = bi & (L_TOK - 1);
    int j = threadIdx.x;        // 0..127
    int nj = (b << 7) + j;

    __shared__ float xi[C_ATOM][3];
    __shared__ float sqi_s[C_ATOM];
    __shared__ int   padi[C_ATOM];
    if (j < C_ATOM) {
        float x0 = X[((size_t)bi * C_ATOM + j) * 3 + 0];
        float x1 = X[((size_t)bi * C_ATOM + j) * 3 + 1];
        float x2 = X[((size_t)bi * C_ATOM + j) * 3 + 2];
        xi[j][0] = x0; xi[j][1] = x1; xi[j][2] = x2;
        sqi_s[j] = sq3(x0, x1, x2);
        padi[j] = (AP[bi * C_ATOM + j] == 0);
    }
    __syncthreads();

    float xj[C_ATOM][3], sqj[C_ATOM];
    unsigned pj = 0;
    for (int c = 0; c < C_ATOM; ++c) {
        float x0 = X[((size_t)nj * C_ATOM + c) * 3 + 0];
        float x1 = X[((size_t)nj * C_ATOM + c) * 3 + 1];
        float x2 = X[((size_t)nj * C_ATOM + c) * 3 + 2];
        xj[c][0] = x0; xj[c][1] = x1; xj[c][2] = x2;
        sqj[c] = sq3(x0, x1, x2);
        if (AP[nj * C_ATOM + c] == 0) pj |= (1u << c);
    }

    // min over valid atom pairs of d2 = (sq_i + sq_j) - 2*dot  (reference assoc order)
    float mind2 = FLT_MAX;
    for (int a = 0; a < C_ATOM; ++a) {
        if (padi[a]) continue;
        float a0 = xi[a][0], a1 = xi[a][1], a2 = xi[a][2];
        float sa = sqi_s[a];
        for (int c = 0; c < C_ATOM; ++c) {
            if (pj & (1u << c)) continue;
            float dot = __fadd_rn(__fadd_rn(__fmul_rn(a0, xj[c][0]),
                                            __fmul_rn(a1, xj[c][1])),
                                  __fmul_rn(a2, xj[c][2]));
            float d2 = __fsub_rn(__fadd_rn(sa, sqj[c]), __fmul_rn(2.0f, dot));
            mind2 = fminf(mind2, d2);
        }
    }
    // sqrt/max are monotone -> commutes with min; bitwise equal to ref's min of sqrts
    float dij = sqrtf(fmaxf(mind2, 0.0f));

    int si = S[bi], sj = S[nj];
    int segi = seg[bi], segj = seg[nj];
    bool gi = si >= 21, gj = sj >= 21;
    bool notself = (j != i);
    bool inner = (segi == segj) && !gi && !gj && notself;
    bool outer = (segi != segj) && !gi && !gj && notself;

    __shared__ float dmaster[L_TOK];
    __shared__ float dv[L_TOK];
    __shared__ int   di[L_TOK];

    for (int pass = 0; pass < 2; ++pass) {
        bool m = (pass == 0) ? inner : outer;
        float* osrc = (pass == 0) ? ctx_src : int_src;
        float* odst = (pass == 0) ? ctx_dst : int_dst;
        float* oval = (pass == 0) ? ctx_val : int_val;
        dmaster[j] = m ? dij : BIGINT_F;
        __syncthreads();
        for (int k = 0; k < K_NB; ++k) {
            dv[j] = dmaster[j];
            di[j] = j;
            __syncthreads();
            // stable min-reduce: strictly-less wins; tie -> smaller index (matches top_k)
            for (int s = 64; s > 0; s >>= 1) {
                if (j < s) {
                    float od = dv[j + s]; int oi = di[j + s];
                    if (od < dv[j] || (od == dv[j] && oi < di[j])) { dv[j] = od; di[j] = oi; }
                }
                __syncthreads();
            }
            if (j == 0) {
                float dmin = dv[0];
                int jmin = di[0];
                bool valid = dmin < BIGINT_F;
                int o = bi * K_NB + k;
                osrc[o] = valid ? (float)bi : -1.0f;
                odst[o] = valid ? (float)((b << 7) + jmin) : -1.0f;
                oval[o] = valid ? 1.0f : 0.0f;
                dmaster[jmin] = FLT_MAX;  // exclude for subsequent picks
            }
            __syncthreads();
        }
    }
}

// ---------------- extra_ctx_adj ------------------------------------------------------
__global__ void adj_kernel(const int* __restrict__ S, const int* __restrict__ seg,
                           float* __restrict__ out) {
    int idx = blockIdx.x * blockDim.x + threadIdx.x;  // over B*L*L
    int b = idx >> 14;
    int i = (idx >> 7) & (L_TOK - 1);
    int j = idx & (L_TOK - 1);
    int ni = (b << 7) + i, nj = (b << 7) + j;
    bool gi = S[ni] >= 21, gj = S[nj] >= 21;
    int segi = seg[ni], segj = seg[nj];
    bool notself = (i != j);
    bool same = (segi == segj);
    bool gn = same && (gi || gj) && notself;        // global_normal
    bool gg = gi && gj && notself;                  // global_global
    int d = i - j;
    bool adjacent = (d == 1 || d == -1);
    bool sm = adjacent && !(gi || gj) && (segi != 1);  // seq_mask (AG_SEG=1)
    out[idx] = (gn || gg || sm) ? 1.0f : 0.0f;
}

extern "C" void kernel_launch(void* const* d_in, const int* in_sizes, int n_in,
                              void* d_out, int out_size, void* d_ws, size_t ws_size,
                              hipStream_t stream) {
    const int*   S    = (const int*)d_in[0];
    const int*   RP   = (const int*)d_in[1];
    const int*   A    = (const int*)d_in[2];
    const int*   AP   = (const int*)d_in[3];
    const float* X    = (const float*)d_in[4];
    const int*   seg  = (const int*)d_in[5];
    const float* rese = (const float*)d_in[6];
    const float* atme = (const float*)d_in[7];
    const float* atpe = (const float*)d_in[8];

    const int N = in_sizes[0];       // 2048
    const int B = N / L_TOK;         // 16
    float* out = (float*)d_out;

    // flat output layout (all float32)
    size_t off = 0;
    float* h_out = out + off;              off += (size_t)N * 2 * E_DIM;       // h
    float* ctx_src = out + off;            off += (size_t)N * K_NB;            // ctx_knn row 0
    float* ctx_dst = out + off;            off += (size_t)N * K_NB;            // ctx_knn row 1
    float* ctx_val = out + off;            off += (size_t)N * K_NB;            // ctx_valid
    float* adj_out = out + off;            off += (size_t)B * L_TOK * L_TOK;   // extra_ctx_adj
    float* int_src = out + off;            off += (size_t)N * K_NB;            // inter_knn row 0
    float* int_dst = out + off;            off += (size_t)N * K_NB;            // inter_knn row 1
    float* int_val = out + off;            off += (size_t)N * K_NB;            // inter_valid

    embed_kernel<<<N, E_DIM, 0, stream>>>(S, RP, A, AP, rese, atme, atpe, h_out);
    knn_kernel<<<N, L_TOK, 0, stream>>>(X, AP, S, seg,
                                        ctx_src, ctx_dst, ctx_val,
                                        int_src, int_dst, int_val);
    int adj_total = B * L_TOK * L_TOK;
    adj_kernel<<<adj_total / 256, 256, 0, stream>>>(S, seg, adj_out);
}

// Round 2
// 97.455 us; speedup vs baseline: 1.2278x; 1.2278x over previous
//
#include <hip/hip_runtime.h>
#include <math.h>
#include <float.h>
#include <stdint.h>

#define BIGINT_F 1e10f
#define L_TOK 128
#define C_ATOM 14
#define E_DIM 256
#define K_NB 9

// strict f32: ((x*x + y*y) + z*z), no FMA contraction (match np order)
__device__ __forceinline__ float sq3(float x, float y, float z) {
    return __fadd_rn(__fadd_rn(__fmul_rn(x, x), __fmul_rn(y, y)), __fmul_rn(z, z));
}

__device__ __forceinline__ uint64_t umin64(uint64_t a, uint64_t b) { return a < b ? a : b; }

// One fused kernel. Block roles by blockIdx.x:
//   [0, NKNN)            : knn — 4 waves/block, one wave per row (b,i)
//   [NKNN, NKNN+N)       : embed — one block per token n
//   [NKNN+N, ...)        : adj — 256 elements per block
__global__ void __launch_bounds__(256)
fused_kernel(const int* __restrict__ S, const int* __restrict__ RP,
             const int* __restrict__ A, const int* __restrict__ AP,
             const float* __restrict__ X, const int* __restrict__ seg,
             const float* __restrict__ res_embed,
             const float* __restrict__ atom_embed,
             const float* __restrict__ atom_pos_embed,
             float* __restrict__ h,
             float* __restrict__ ctx_src, float* __restrict__ ctx_dst, float* __restrict__ ctx_val,
             float* __restrict__ adj_out,
             float* __restrict__ int_src, float* __restrict__ int_dst, float* __restrict__ int_val,
             int N) {
    const int NKNN = N / 4;          // 4 rows per block (one per wave)
    int blk = blockIdx.x;
    int tid = threadIdx.x;

    if (blk < NKNN) {
        // ----------------- KNN: wave-per-row, shfl-butterfly selection -----------------
        int wave = tid >> 6;
        int lane = tid & 63;
        int bi = blk * 4 + wave;             // b*L + i
        int b  = bi >> 7;
        int i  = bi & (L_TOK - 1);

        __shared__ float4 sxi[4][C_ATOM];
        if (lane < C_ATOM) {
            const float* xp = X + ((size_t)bi * C_ATOM + lane) * 3;
            float x0 = xp[0], x1 = xp[1], x2 = xp[2];
            float sq = (AP[bi * C_ATOM + lane] == 0) ? INFINITY : sq3(x0, x1, x2);
            sxi[wave][lane] = make_float4(x0, x1, x2, sq);
        }
        __syncthreads();   // block-uniform path: safe

        float xa0[C_ATOM], xa1[C_ATOM], xa2[C_ATOM], sa[C_ATOM];
        #pragma unroll
        for (int a = 0; a < C_ATOM; ++a) {
            float4 t = sxi[wave][a];
            xa0[a] = t.x; xa1[a] = t.y; xa2[a] = t.z; sa[a] = t.w;
        }

        int j0 = lane, j1 = lane + 64;
        int nj0 = (b << 7) + j0, nj1 = (b << 7) + j1;

        float mind0 = INFINITY, mind1 = INFINITY;
        for (int c = 0; c < C_ATOM; ++c) {
            const float* yp0 = X + ((size_t)nj0 * C_ATOM + c) * 3;
            const float* yp1 = X + ((size_t)nj1 * C_ATOM + c) * 3;
            float y00 = yp0[0], y01 = yp0[1], y02 = yp0[2];
            float y10 = yp1[0], y11 = yp1[1], y12 = yp1[2];
            float sc0 = (AP[nj0 * C_ATOM + c] == 0) ? INFINITY : sq3(y00, y01, y02);
            float sc1 = (AP[nj1 * C_ATOM + c] == 0) ? INFINITY : sq3(y10, y11, y12);
            #pragma unroll
            for (int a = 0; a < C_ATOM; ++a) {
                float dot0 = __fadd_rn(__fadd_rn(__fmul_rn(xa0[a], y00),
                                                 __fmul_rn(xa1[a], y01)),
                                       __fmul_rn(xa2[a], y02));
                float d20 = __fsub_rn(__fadd_rn(sa[a], sc0), __fmul_rn(2.0f, dot0));
                mind0 = fminf(mind0, d20);
                float dot1 = __fadd_rn(__fadd_rn(__fmul_rn(xa0[a], y10),
                                                 __fmul_rn(xa1[a], y11)),
                                       __fmul_rn(xa2[a], y12));
                float d21 = __fsub_rn(__fadd_rn(sa[a], sc1), __fmul_rn(2.0f, dot1));
                mind1 = fminf(mind1, d21);
            }
        }
        float d0 = sqrtf(fmaxf(mind0, 0.0f));
        float d1 = sqrtf(fmaxf(mind1, 0.0f));

        int si = S[bi];
        int segi = seg[bi];
        bool gi = si >= 21;
        int sj0 = S[nj0], sj1 = S[nj1];
        int segj0 = seg[nj0], segj1 = seg[nj1];
        bool gj0 = sj0 >= 21, gj1 = sj1 >= 21;
        bool ng0 = !gi && !gj0 && (j0 != i);
        bool ng1 = !gi && !gj1 && (j1 != i);
        bool inner0 = (segi == segj0) && ng0;
        bool inner1 = (segi == segj1) && ng1;
        bool outer0 = (segi != segj0) && ng0;
        bool outer1 = (segi != segj1) && ng1;

        const uint32_t bigbits = __float_as_uint(BIGINT_F);
        uint64_t kd0 = ((uint64_t)__float_as_uint(d0) << 32) | (uint32_t)j0;
        uint64_t kd1 = ((uint64_t)__float_as_uint(d1) << 32) | (uint32_t)j1;
        uint64_t kbig0 = ((uint64_t)bigbits << 32) | (uint32_t)j0;
        uint64_t kbig1 = ((uint64_t)bigbits << 32) | (uint32_t)j1;

        for (int pass = 0; pass < 2; ++pass) {
            uint64_t k0 = (pass == 0 ? inner0 : outer0) ? kd0 : kbig0;
            uint64_t k1 = (pass == 0 ? inner1 : outer1) ? kd1 : kbig1;
            float* osrc = (pass == 0) ? ctx_src : int_src;
            float* odst = (pass == 0) ? ctx_dst : int_dst;
            float* oval = (pass == 0) ? ctx_val : int_val;
            #pragma unroll
            for (int k = 0; k < K_NB; ++k) {
                uint64_t kk = umin64(k0, k1);
                #pragma unroll
                for (int m = 32; m > 0; m >>= 1) {
                    uint64_t o = __shfl_xor((unsigned long long)kk, m, 64);
                    kk = umin64(kk, o);
                }
                if (k0 == kk) k0 = UINT64_MAX;
                if (k1 == kk) k1 = UINT64_MAX;
                if (lane == 0) {
                    uint32_t dbits = (uint32_t)(kk >> 32);
                    int jmin = (int)(uint32_t)kk;
                    bool valid = dbits < bigbits;   // d < BIGINT strictly
                    int o = bi * K_NB + k;
                    osrc[o] = valid ? (float)bi : -1.0f;
                    odst[o] = valid ? (float)((b << 7) + jmin) : -1.0f;
                    oval[o] = valid ? 1.0f : 0.0f;
                }
            }
        }
    } else if (blk < NKNN + N) {
        // ----------------- EMBED: one block per token -----------------
        int n = blk - NKNN;
        int e = tid;  // 0..255
        int s = S[n];
        float rp = (float)RP[n];

        int k = e >> 1;
        // 10000^(-2k/E) = exp2(k * (-2*log2(10000)/E))
        const float c1 = (float)(-2.0 * 13.287712379549449 / (double)E_DIM);
        float invk = exp2f((float)k * c1);
        float ang = rp * invk;
        float pe = (e & 1) ? cosf(ang) : sinf(ang);
        h[(size_t)n * (2 * E_DIM) + e] = res_embed[s * E_DIM + e] + pe;

        __shared__ int sA[C_ATOM], sAP[C_ATOM];
        if (e < C_ATOM) { sA[e] = A[n * C_ATOM + e]; sAP[e] = AP[n * C_ATOM + e]; }
        __syncthreads();

        float sum = 0.0f, cnt = 0.0f;
        for (int c = 0; c < C_ATOM; ++c) {
            if (sAP[c] != 0) {
                sum += atom_embed[sA[c] * E_DIM + e] + atom_pos_embed[sAP[c] * E_DIM + e];
                cnt += 1.0f;
            }
        }
        h[(size_t)n * (2 * E_DIM) + E_DIM + e] = sum / (cnt + 1e-10f);
    } else {
        // ----------------- ADJ -----------------
        int idx = (blk - NKNN - N) * 256 + tid;   // over B*L*L
        int b = idx >> 14;
        int i = (idx >> 7) & (L_TOK - 1);
        int j = idx & (L_TOK - 1);
        int ni = (b << 7) + i, nj = (b << 7) + j;
        bool gi = S[ni] >= 21, gj = S[nj] >= 21;
        int segi = seg[ni], segj = seg[nj];
        bool notself = (i != j);
        bool same = (segi == segj);
        bool gn = same && (gi || gj) && notself;
        bool gg = gi && gj && notself;
        int d = i - j;
        bool adjacent = (d == 1 || d == -1);
        bool sm = adjacent && !(gi || gj) && (segi != 1);  // AG_SEG=1
        adj_out[idx] = (gn || gg || sm) ? 1.0f : 0.0f;
    }
}

extern "C" void kernel_launch(void* const* d_in, const int* in_sizes, int n_in,
                              void* d_out, int out_size, void* d_ws, size_t ws_size,
                              hipStream_t stream) {
    const int*   S    = (const int*)d_in[0];
    const int*   RP   = (const int*)d_in[1];
    const int*   A    = (const int*)d_in[2];
    const int*   AP   = (const int*)d_in[3];
    const float* X    = (const float*)d_in[4];
    const int*   seg  = (const int*)d_in[5];
    const float* rese = (const float*)d_in[6];
    const float* atme = (const float*)d_in[7];
    const float* atpe = (const float*)d_in[8];

    const int N = in_sizes[0];       // 2048
    const int B = N / L_TOK;         // 16
    float* out = (float*)d_out;

    size_t off = 0;
    float* h_out   = out + off;  off += (size_t)N * 2 * E_DIM;
    float* ctx_src = out + off;  off += (size_t)N * K_NB;
    float* ctx_dst = out + off;  off += (size_t)N * K_NB;
    float* ctx_val = out + off;  off += (size_t)N * K_NB;
    float* adj_out = out + off;  off += (size_t)B * L_TOK * L_TOK;
    float* int_src = out + off;  off += (size_t)N * K_NB;
    float* int_dst = out + off;  off += (size_t)N * K_NB;
    float* int_val = out + off;  off += (size_t)N * K_NB;

    int nknn = N / 4;                          // 512
    int nadj = (B * L_TOK * L_TOK) / 256;      // 1024
    int grid = nknn + N + nadj;                // 3584
    fused_kernel<<<grid, 256, 0, stream>>>(S, RP, A, AP, X, seg, rese, atme, atpe,
                                           h_out, ctx_src, ctx_dst, ctx_val,
                                           adj_out, int_src, int_dst, int_val, N);
}